// Round 8
// baseline (649.443 us; speedup 1.0000x reference)
//
#include <hip/hip_runtime.h>
#include <hip/hip_bf16.h>

// Joiner: out[b,t,u,v] = tanh(enc[b,t,:] + pred[b,u,:]) . W[v,:] + bias[v]
// B=8 T=512 U=128 D=256 V=128, fp32 in/out.
// R8 structure: NO in-loop barriers. W (bf16, 64 KB) staged once per block
// into XOR-swizzled LDS; joint/tanh values are computed in registers directly
// in MFMA B-fragment layout (the computing thread IS the consuming thread),
// so the joint tile never touches LDS and waves run free -> stores, tanh
// VALU, LDS reads and MFMA overlap across the 16 waves/CU.
// Block = (b, 8-t chunk), 512 thr = 8 waves; wave w = u-rows [w*16, w*16+16),
// all 128 v. pred row persists in regs as bf16 (32 VGPR); acc 32 VGPR.

constexpr int Bn = 8, Tn = 512, Un = 128, Dn = 256, Vn = 128;
constexpr int TCHUNK = 8;

typedef __attribute__((ext_vector_type(8))) short bf16x8;   // 8 bf16 = 4 VGPRs
typedef __attribute__((ext_vector_type(4))) float f32x4;

static __device__ __forceinline__ unsigned short f2bf(float f) {
    unsigned int u = __float_as_uint(f);
    return (unsigned short)((u + 0x7fffu + ((u >> 16) & 1u)) >> 16);
}
static __device__ __forceinline__ float bf2f(unsigned short h) {
    return __uint_as_float(((unsigned int)h) << 16);
}
// tanh(x) = 1 - 2/(exp(2x)+1); med3 clamp (R5-proven form)
static __device__ __forceinline__ float fast_tanh(float x) {
    float t = __builtin_amdgcn_fmed3f(x, -8.f, 8.f);
    float e = __expf(2.f * t);
    float r = __builtin_amdgcn_rcpf(e + 1.f);
    return __builtin_fmaf(-2.f, r, 1.f);
}

__global__ __launch_bounds__(256) void cvtW_kernel(const float* __restrict__ W,
                                                   unsigned short* __restrict__ Wb) {
    int i = blockIdx.x * 256 + threadIdx.x;          // 32 blocks * 256 * 4 elems = 32768
    float4 v = ((const float4*)W)[i];
    unsigned short r0 = f2bf(v.x), r1 = f2bf(v.y), r2 = f2bf(v.z), r3 = f2bf(v.w);
    unsigned long long packed = (unsigned long long)r0 | ((unsigned long long)r1 << 16) |
                                ((unsigned long long)r2 << 32) | ((unsigned long long)r3 << 48);
    ((unsigned long long*)Wb)[i] = packed;
}

__global__ __launch_bounds__(512, 4) void joiner_kernel(
    const float* __restrict__ enc,         // [B,T,D]
    const float* __restrict__ pred,        // [B,U,D]
    const unsigned short* __restrict__ Wb, // [V,D] bf16 bits
    const float* __restrict__ bias,        // [V]
    float* __restrict__ out)               // [B,T,U,V]
{
    // W in LDS: 128 v-rows x 256 d (bf16) as 16B granules; granule g of row v
    // stored at g ^ (v&7). Read pattern (kk*4+lq)^(l16&7) == the R5-verified
    // 0-conflict pattern.
    __shared__ unsigned short Wl[128 * 256];   // 64 KB

    const int bid = blockIdx.x;            // b*64 + tchunk
    const int tch = bid & 63;
    const int b   = bid >> 6;
    const int tid = threadIdx.x;
    const int w   = tid >> 6;              // wave 0..7 -> u-rows [w*16, w*16+16)
    const int l16 = tid & 15;
    const int lq  = (tid >> 4) & 3;

    // ---- stage W (bf16) into swizzled LDS: thread = (row v = tid>>2, quarter) ----
    {
        const int v    = tid >> 2;
        const int part = tid & 3;
        const unsigned short* src = Wb + (size_t)v * Dn + part * 64;
#pragma unroll
        for (int i = 0; i < 8; ++i) {
            bf16x8 q = *(const bf16x8*)(src + i * 8);
            const int g = (part * 8 + i) ^ (v & 7);
            *(bf16x8*)&Wl[((size_t)v * 32 + g) * 8] = q;
        }
    }

    // ---- pred row for this lane, bf16, already in MFMA B-frag layout ----
    const int u = w * 16 + l16;            // this lane's u row (B n-index = l16)
    bf16x8 predR[8];                       // [kk]: d = kk*32 + lq*8 .. +7
    {
        const float* pr = pred + ((size_t)(b * Un + u)) * Dn + lq * 8;
#pragma unroll
        for (int kk = 0; kk < 8; ++kk) {
            float4 a0 = *(const float4*)(pr + kk * 32);
            float4 a1 = *(const float4*)(pr + kk * 32 + 4);
            bf16x8 q;
            q[0] = (short)f2bf(a0.x); q[1] = (short)f2bf(a0.y);
            q[2] = (short)f2bf(a0.z); q[3] = (short)f2bf(a0.w);
            q[4] = (short)f2bf(a1.x); q[5] = (short)f2bf(a1.y);
            q[6] = (short)f2bf(a1.z); q[7] = (short)f2bf(a1.w);
            predR[kk] = q;
        }
    }

    __syncthreads();   // the ONLY barrier: W staging visible to all waves

    const float* encRow0 = enc + ((size_t)(b * Tn + tch * TCHUNK)) * Dn + lq * 8;

    for (int ti = 0; ti < TCHUNK; ++ti) {
        const float* er = encRow0 + (size_t)ti * Dn;

        f32x4 acc[8];                      // v-tiles mt=0..7 (128 v total)
#pragma unroll
        for (int mt = 0; mt < 8; ++mt) acc[mt] = (f32x4){0.f, 0.f, 0.f, 0.f};

#pragma unroll
        for (int kk = 0; kk < 8; ++kk) {
            // enc octet (L1-broadcast: 16 lanes share each address)
            float4 e0 = *(const float4*)(er + kk * 32);
            float4 e1 = *(const float4*)(er + kk * 32 + 4);
            const float ev[8] = {e0.x, e0.y, e0.z, e0.w, e1.x, e1.y, e1.z, e1.w};

            // joint B-frag in registers: tanh(enc+pred) for (u=l16 row, d-octet)
            bf16x8 jf;
#pragma unroll
            for (int i = 0; i < 8; ++i)
                jf[i] = (short)f2bf(fast_tanh(ev[i] + bf2f((unsigned short)predR[kk][i])));

            // A = W v-rows from LDS (R5-verified conflict-free pattern)
#pragma unroll
            for (int mt = 0; mt < 8; ++mt) {
                const int row = mt * 16 + l16;
                bf16x8 wf = *(const bf16x8*)&Wl[((size_t)row * 32
                                                 + ((kk * 4 + lq) ^ (l16 & 7))) * 8];
                acc[mt] = __builtin_amdgcn_mfma_f32_16x16x32_bf16(wf, jf, acc[mt], 0, 0, 0);
            }
        }

        // epilogue: D row = v = lq*4+r (float4 along v), col = u = l16
        float* ob = out + ((size_t)((b * Tn + tch * TCHUNK + ti) * Un + u)) * Vn + lq * 4;
#pragma unroll
        for (int mt = 0; mt < 8; ++mt) {
            float4 bv = *(const float4*)(bias + mt * 16 + lq * 4);
            f32x4 rv;
            rv[0] = acc[mt][0] + bv.x;
            rv[1] = acc[mt][1] + bv.y;
            rv[2] = acc[mt][2] + bv.z;
            rv[3] = acc[mt][3] + bv.w;
            *(f32x4*)(ob + mt * 16) = rv;
        }
    }
}

extern "C" void kernel_launch(void* const* d_in, const int* in_sizes, int n_in,
                              void* d_out, int out_size, void* d_ws, size_t ws_size,
                              hipStream_t stream) {
    const float* enc  = (const float*)d_in[0];
    const float* pred = (const float*)d_in[1];
    const float* W    = (const float*)d_in[2];
    const float* bias = (const float*)d_in[3];
    float* out = (float*)d_out;
    unsigned short* Wb = (unsigned short*)d_ws;   // 32768 bf16 = 64 KB

    cvtW_kernel<<<32, 256, 0, stream>>>(W, Wb);
    // grid = B * (T/TCHUNK) = 8 * 64 = 512 blocks of 512 threads
    joiner_kernel<<<512, 512, 0, stream>>>(enc, pred, Wb, bias, out);
}

// Round 9
// 477.246 us; speedup vs baseline: 1.3608x; 1.3608x over previous
//
#include <hip/hip_runtime.h>
#include <hip/hip_bf16.h>

// Joiner: out[b,t,u,v] = tanh(enc[b,t,:] + pred[b,u,:]) . W[v,:] + bias[v]
// B=8 T=512 U=128 D=256 V=128, fp32 in/out.
// R9: barrier-free steady state (R8 mechanism) with R1-style register fit.
// Block = 256 thr = 4 waves = (b, 8-t chunk, u-half, v-half); wave = 16u x 64v.
// W v-half (64 rows x 256 d bf16, 32 KB) staged once into XOR-swizzled LDS
// (one __syncthreads total). Joint/tanh computed in registers directly in
// MFMA B-frag layout (computing thread == consuming thread) -> no joint LDS,
// no in-loop barriers; stores, tanh VALU, LDS reads and MFMA overlap across
// 16 waves/CU. pred row persists as bf16 (32 VGPR); acc = 16 VGPR.

constexpr int Bn = 8, Tn = 512, Un = 128, Dn = 256, Vn = 128;
constexpr int TCHUNK = 8;

typedef __attribute__((ext_vector_type(8))) short bf16x8;   // 8 bf16 = 4 VGPRs
typedef __attribute__((ext_vector_type(4))) float f32x4;

static __device__ __forceinline__ unsigned short f2bf(float f) {
    unsigned int u = __float_as_uint(f);
    return (unsigned short)((u + 0x7fffu + ((u >> 16) & 1u)) >> 16);
}
static __device__ __forceinline__ float bf2f(unsigned short h) {
    return __uint_as_float(((unsigned int)h) << 16);
}
// tanh(x) = 1 - 2/(exp(2x)+1); no clamp needed: e->inf gives 1, e->0 gives -1
static __device__ __forceinline__ float fast_tanh(float x) {
    float e = __expf(2.f * x);
    float r = __builtin_amdgcn_rcpf(e + 1.f);
    return __builtin_fmaf(-2.f, r, 1.f);
}

__global__ __launch_bounds__(256) void cvtW_kernel(const float* __restrict__ W,
                                                   unsigned short* __restrict__ Wb) {
    int i = blockIdx.x * 256 + threadIdx.x;          // 32 blocks * 256 * 4 elems = 32768
    float4 v = ((const float4*)W)[i];
    unsigned short r0 = f2bf(v.x), r1 = f2bf(v.y), r2 = f2bf(v.z), r3 = f2bf(v.w);
    unsigned long long packed = (unsigned long long)r0 | ((unsigned long long)r1 << 16) |
                                ((unsigned long long)r2 << 32) | ((unsigned long long)r3 << 48);
    ((unsigned long long*)Wb)[i] = packed;
}

__global__ __launch_bounds__(256, 4) void joiner_kernel(
    const float* __restrict__ enc,         // [B,T,D]
    const float* __restrict__ pred,        // [B,U,D]
    const unsigned short* __restrict__ Wb, // [V,D] bf16 bits
    const float* __restrict__ bias,        // [V]
    float* __restrict__ out)               // [B,T,U,V]
{
    // W v-half in LDS: 64 rows x 256 d (bf16) as 16B granules; granule g of
    // row v stored at g ^ (v&7); read pattern (kk*4+lq)^(l16&7) (R5-proven).
    __shared__ unsigned short Wl[64 * 256];   // 32 KB

    const int bid = blockIdx.x;            // ((b*64 + tc)*2 + uh)*2 + vh
    const int vh  = bid & 1;
    const int uh  = (bid >> 1) & 1;
    const int tc  = (bid >> 2) & 63;
    const int b   = bid >> 8;
    const int tid = threadIdx.x;
    const int w   = tid >> 6;              // wave 0..3 -> u rows [w*16, w*16+16)
    const int l16 = tid & 15;
    const int lq  = (tid >> 4) & 3;

    // ---- stage W half (rows vh*64 .. +64) into swizzled LDS ----
    {
        const int vloc = tid >> 2;         // 0..63
        const int part = tid & 3;
        const unsigned short* src = Wb + (size_t)(vh * 64 + vloc) * Dn + part * 64;
#pragma unroll
        for (int i = 0; i < 8; ++i) {
            bf16x8 q = *(const bf16x8*)(src + i * 8);
            const int g = (part * 8 + i) ^ (vloc & 7);
            *(bf16x8*)&Wl[((size_t)vloc * 32 + g) * 8] = q;
        }
    }

    // ---- pred row for this lane, bf16, already in MFMA B-frag layout ----
    const int u = uh * 64 + w * 16 + l16;  // B-operand n-index = l16
    bf16x8 predR[8];                       // [kk]: d = kk*32 + lq*8 .. +7
    {
        const float* pr = pred + ((size_t)(b * Un + u)) * Dn + lq * 8;
#pragma unroll
        for (int kk = 0; kk < 8; ++kk) {
            float4 a0 = *(const float4*)(pr + kk * 32);
            float4 a1 = *(const float4*)(pr + kk * 32 + 4);
            bf16x8 q;
            q[0] = (short)f2bf(a0.x); q[1] = (short)f2bf(a0.y);
            q[2] = (short)f2bf(a0.z); q[3] = (short)f2bf(a0.w);
            q[4] = (short)f2bf(a1.x); q[5] = (short)f2bf(a1.y);
            q[6] = (short)f2bf(a1.z); q[7] = (short)f2bf(a1.w);
            predR[kk] = q;
        }
    }

    __syncthreads();   // the ONLY barrier: W staging visible to the 4 waves

    const float* encRow0 = enc + ((size_t)(b * Tn + tc * TCHUNK)) * Dn + lq * 8;

    for (int ti = 0; ti < TCHUNK; ++ti) {
        const float* er = encRow0 + (size_t)ti * Dn;

        f32x4 acc[4];                      // v-tiles mt=0..3 (64 v total)
#pragma unroll
        for (int mt = 0; mt < 4; ++mt) acc[mt] = (f32x4){0.f, 0.f, 0.f, 0.f};

#pragma unroll
        for (int kk = 0; kk < 8; ++kk) {
            // enc octet (L1-broadcast: 16 lanes share each address)
            float4 e0 = *(const float4*)(er + kk * 32);
            float4 e1 = *(const float4*)(er + kk * 32 + 4);
            const float ev[8] = {e0.x, e0.y, e0.z, e0.w, e1.x, e1.y, e1.z, e1.w};

            // joint B-frag in registers: tanh(enc+pred) for (u=l16 row, d-octet)
            bf16x8 jf;
#pragma unroll
            for (int i = 0; i < 8; ++i)
                jf[i] = (short)f2bf(fast_tanh(ev[i] + bf2f((unsigned short)predR[kk][i])));

            // A = W v-rows from swizzled LDS; 4 MFMAs accumulate 64 v
#pragma unroll
            for (int mt = 0; mt < 4; ++mt) {
                const int row = mt * 16 + l16;
                bf16x8 wf = *(const bf16x8*)&Wl[((size_t)row * 32
                                                 + ((kk * 4 + lq) ^ (l16 & 7))) * 8];
                acc[mt] = __builtin_amdgcn_mfma_f32_16x16x32_bf16(wf, jf, acc[mt], 0, 0, 0);
            }
        }

        // epilogue: D row = v-in-tile = lq*4+r (float4 along v), col = u = l16
        float* ob = out + ((size_t)((b * Tn + tc * TCHUNK + ti) * Un + u)) * Vn
                        + vh * 64 + lq * 4;
#pragma unroll
        for (int mt = 0; mt < 4; ++mt) {
            float4 bv = *(const float4*)(bias + vh * 64 + mt * 16 + lq * 4);
            f32x4 rv;
            rv[0] = acc[mt][0] + bv.x;
            rv[1] = acc[mt][1] + bv.y;
            rv[2] = acc[mt][2] + bv.z;
            rv[3] = acc[mt][3] + bv.w;
            *(f32x4*)(ob + mt * 16) = rv;
        }
    }
}

extern "C" void kernel_launch(void* const* d_in, const int* in_sizes, int n_in,
                              void* d_out, int out_size, void* d_ws, size_t ws_size,
                              hipStream_t stream) {
    const float* enc  = (const float*)d_in[0];
    const float* pred = (const float*)d_in[1];
    const float* W    = (const float*)d_in[2];
    const float* bias = (const float*)d_in[3];
    float* out = (float*)d_out;
    unsigned short* Wb = (unsigned short*)d_ws;   // 32768 bf16 = 64 KB

    cvtW_kernel<<<32, 256, 0, stream>>>(W, Wb);
    // grid = B * (T/TCHUNK) * 2 u-halves * 2 v-halves = 8*64*2*2 = 2048 blocks
    joiner_kernel<<<2048, 256, 0, stream>>>(enc, pred, Wb, bias, out);
}

// Round 10
// 184.477 us; speedup vs baseline: 3.5205x; 2.5870x over previous
//
#include <hip/hip_runtime.h>
#include <hip/hip_bf16.h>

// Joiner: out[b,t,u,v] = tanh(enc[b,t,:] + pred[b,u,:]) . W[v,:] + bias[v]
// B=8 T=512 U=128 D=256 V=128, fp32 in/out.
// R10: R8's barrier-free dataflow at a register-feasible size.
//  - Block = 256 thr = 4 waves = (b, 8-t chunk, u-half of 64); all 128 v.
//  - W (bf16, 128x256, 64 KB) staged once into XOR-swizzled LDS; ONE barrier.
//  - joint/tanh computed once, in registers, directly in MFMA B-frag layout
//    (computing thread == consuming thread) -> no joint LDS, no in-loop
//    barriers; stores, tanh VALU, LDS reads, MFMA overlap across waves.
//  - NO min-occupancy launch_bounds arg: sessions R7/R8/R9 proved
//    __launch_bounds__(N,4) forces a 64-VGPR cap -> catastrophic spill.
//    Plain __launch_bounds__(256) allows ~128 VGPR (R1: 80, clean).

constexpr int Bn = 8, Tn = 512, Un = 128, Dn = 256, Vn = 128;
constexpr int TCHUNK = 8;

typedef __attribute__((ext_vector_type(8))) short bf16x8;   // 8 bf16 = 4 VGPRs
typedef __attribute__((ext_vector_type(4))) float f32x4;

static __device__ __forceinline__ unsigned short f2bf(float f) {
    unsigned int u = __float_as_uint(f);
    return (unsigned short)((u + 0x7fffu + ((u >> 16) & 1u)) >> 16);
}
static __device__ __forceinline__ float bf2f(unsigned short h) {
    return __uint_as_float(((unsigned int)h) << 16);
}
// tanh(x) = 1 - 2/(exp(2x)+1); no clamp: e->inf => 1, e->0 => -1 (exact limits)
static __device__ __forceinline__ float fast_tanh(float x) {
    float e = __expf(2.f * x);
    float r = __builtin_amdgcn_rcpf(e + 1.f);
    return __builtin_fmaf(-2.f, r, 1.f);
}

__global__ __launch_bounds__(256) void cvtW_kernel(const float* __restrict__ W,
                                                   unsigned short* __restrict__ Wb) {
    int i = blockIdx.x * 256 + threadIdx.x;          // 32 blocks * 256 * 4 elems = 32768
    float4 v = ((const float4*)W)[i];
    unsigned short r0 = f2bf(v.x), r1 = f2bf(v.y), r2 = f2bf(v.z), r3 = f2bf(v.w);
    unsigned long long packed = (unsigned long long)r0 | ((unsigned long long)r1 << 16) |
                                ((unsigned long long)r2 << 32) | ((unsigned long long)r3 << 48);
    ((unsigned long long*)Wb)[i] = packed;
}

__global__ __launch_bounds__(256) void joiner_kernel(
    const float* __restrict__ enc,         // [B,T,D]
    const float* __restrict__ pred,        // [B,U,D]
    const unsigned short* __restrict__ Wb, // [V,D] bf16 bits
    const float* __restrict__ bias,        // [V]
    float* __restrict__ out)               // [B,T,U,V]
{
    // W in LDS: 128 v-rows x 256 d (bf16) as 16B granules; granule g of row v
    // stored at g ^ (v&7); k-loop read pattern (kk*4+lq)^(l16&7) == the
    // R4/R5-measured 0-conflict pattern.
    __shared__ unsigned short Wl[128 * 256];   // 64 KB -> 2 blocks/CU

    const int bid = blockIdx.x;            // (b*64 + tch)*2 + uh
    const int uh  = bid & 1;
    const int tch = (bid >> 1) & 63;
    const int b   = bid >> 7;
    const int tid = threadIdx.x;
    const int w   = tid >> 6;              // wave 0..3 -> u rows [w*16, w*16+16)
    const int l16 = tid & 15;
    const int lq  = (tid >> 4) & 3;

    // ---- stage full W into swizzled LDS: thread = (row v = tid>>1, half) ----
    {
        const int vloc = tid >> 1;         // 0..127
        const int part = tid & 1;
        const unsigned short* src = Wb + (size_t)vloc * Dn + part * 128;
#pragma unroll
        for (int i = 0; i < 16; ++i) {
            bf16x8 q = *(const bf16x8*)(src + i * 8);
            const int g = (part * 16 + i) ^ (vloc & 7);
            *(bf16x8*)&Wl[((size_t)vloc * 32 + g) * 8] = q;
        }
    }

    // ---- pred row for this lane, bf16, already in MFMA B-frag layout ----
    const int u = uh * 64 + w * 16 + l16;  // B-operand n-index = l16
    bf16x8 predR[8];                       // [kk]: d = kk*32 + lq*8 .. +7
    {
        const float* pr = pred + ((size_t)(b * Un + u)) * Dn + lq * 8;
#pragma unroll
        for (int kk = 0; kk < 8; ++kk) {
            float4 a0 = *(const float4*)(pr + kk * 32);
            float4 a1 = *(const float4*)(pr + kk * 32 + 4);
            bf16x8 q;
            q[0] = (short)f2bf(a0.x); q[1] = (short)f2bf(a0.y);
            q[2] = (short)f2bf(a0.z); q[3] = (short)f2bf(a0.w);
            q[4] = (short)f2bf(a1.x); q[5] = (short)f2bf(a1.y);
            q[6] = (short)f2bf(a1.z); q[7] = (short)f2bf(a1.w);
            predR[kk] = q;
        }
    }

    __syncthreads();   // the ONLY barrier: W staging visible to the 4 waves

    const float* encRow0 = enc + ((size_t)(b * Tn + tch * TCHUNK)) * Dn + lq * 8;

    for (int ti = 0; ti < TCHUNK; ++ti) {
        const float* er = encRow0 + (size_t)ti * Dn;

        f32x4 acc[8];                      // v-tiles mt=0..7 (all 128 v)
#pragma unroll
        for (int mt = 0; mt < 8; ++mt) acc[mt] = (f32x4){0.f, 0.f, 0.f, 0.f};

#pragma unroll
        for (int kk = 0; kk < 8; ++kk) {
            // enc octet (L1-broadcast: 16 lanes share each address)
            float4 e0 = *(const float4*)(er + kk * 32);
            float4 e1 = *(const float4*)(er + kk * 32 + 4);
            const float ev[8] = {e0.x, e0.y, e0.z, e0.w, e1.x, e1.y, e1.z, e1.w};

            // joint B-frag in registers: tanh(enc+pred), computed ONCE
            bf16x8 jf;
#pragma unroll
            for (int i = 0; i < 8; ++i)
                jf[i] = (short)f2bf(fast_tanh(ev[i] + bf2f((unsigned short)predR[kk][i])));

            // A = W v-rows from swizzled LDS; 8 MFMAs accumulate all 128 v
#pragma unroll
            for (int mt = 0; mt < 8; ++mt) {
                const int row = mt * 16 + l16;
                bf16x8 wf = *(const bf16x8*)&Wl[((size_t)row * 32
                                                 + ((kk * 4 + lq) ^ (l16 & 7))) * 8];
                acc[mt] = __builtin_amdgcn_mfma_f32_16x16x32_bf16(wf, jf, acc[mt], 0, 0, 0);
            }
        }

        // epilogue: D row = v = mt*16 + lq*4 + r (float4 along v), col = u = l16;
        // consecutive mt cover adjacent 64B sectors -> full 128B lines in L2.
        float* ob = out + ((size_t)((b * Tn + tch * TCHUNK + ti) * Un + u)) * Vn + lq * 4;
#pragma unroll
        for (int mt = 0; mt < 8; ++mt) {
            float4 bv = *(const float4*)(bias + mt * 16 + lq * 4);
            f32x4 rv;
            rv[0] = acc[mt][0] + bv.x;
            rv[1] = acc[mt][1] + bv.y;
            rv[2] = acc[mt][2] + bv.z;
            rv[3] = acc[mt][3] + bv.w;
            *(f32x4*)(ob + mt * 16) = rv;
        }
    }
}

extern "C" void kernel_launch(void* const* d_in, const int* in_sizes, int n_in,
                              void* d_out, int out_size, void* d_ws, size_t ws_size,
                              hipStream_t stream) {
    const float* enc  = (const float*)d_in[0];
    const float* pred = (const float*)d_in[1];
    const float* W    = (const float*)d_in[2];
    const float* bias = (const float*)d_in[3];
    float* out = (float*)d_out;
    unsigned short* Wb = (unsigned short*)d_ws;   // 32768 bf16 = 64 KB

    cvtW_kernel<<<32, 256, 0, stream>>>(W, Wb);
    // grid = B * (T/TCHUNK) * 2 u-halves = 8 * 64 * 2 = 1024 blocks
    joiner_kernel<<<1024, 256, 0, stream>>>(enc, pred, Wb, bias, out);
}

// Round 11
// 171.843 us; speedup vs baseline: 3.7793x; 1.0735x over previous
//
#include <hip/hip_runtime.h>
#include <hip/hip_bf16.h>

// Joiner: out[b,t,u,v] = tanh(enc[b,t,:] + pred[b,u,:]) . W[v,:] + bias[v]
// B=8 T=512 U=128 D=256 V=128, fp32 in/out.
// R11 = R9 geometry with the launch-bounds fix.
//  - Block = 256 thr = 4 waves = (b, 8-t chunk, u-half, v-half); wave 16u x 64v.
//  - W v-half (64 x 256 bf16 = 32 KB) in XOR-swizzled LDS; ONE barrier total.
//    32 KB LDS => compiler occupancy target ~5 blocks/CU => VGPR target ~102
//    (R10 lesson: 64 KB LDS let the allocator balloon to 204 regs).
//  - joint/tanh computed in registers in MFMA B-frag layout (computing thread
//    == consuming thread): no joint LDS, no in-loop barriers; stores, tanh,
//    LDS reads, MFMA overlap across ~16-20 waves/CU.
//  - NO min-occupancy launch_bounds arg: (N,4) empirically forces a 64-VGPR
//    cap -> catastrophic scratch spill (R7/R8/R9: FETCH 1.1 GB, WRITE +238 MB).

constexpr int Bn = 8, Tn = 512, Un = 128, Dn = 256, Vn = 128;
constexpr int TCHUNK = 8;

typedef __attribute__((ext_vector_type(8))) short bf16x8;   // 8 bf16 = 4 VGPRs
typedef __attribute__((ext_vector_type(4))) float f32x4;

static __device__ __forceinline__ unsigned short f2bf(float f) {
    unsigned int u = __float_as_uint(f);
    return (unsigned short)((u + 0x7fffu + ((u >> 16) & 1u)) >> 16);
}
static __device__ __forceinline__ float bf2f(unsigned short h) {
    return __uint_as_float(((unsigned int)h) << 16);
}
// tanh(x) = 1 - 2/(exp(2x)+1); no clamp: e->inf => 1, e->0 => -1 (exact limits)
static __device__ __forceinline__ float fast_tanh(float x) {
    float e = __expf(2.f * x);
    float r = __builtin_amdgcn_rcpf(e + 1.f);
    return __builtin_fmaf(-2.f, r, 1.f);
}

__global__ __launch_bounds__(256) void cvtW_kernel(const float* __restrict__ W,
                                                   unsigned short* __restrict__ Wb) {
    int i = blockIdx.x * 256 + threadIdx.x;          // 32 blocks * 256 * 4 elems = 32768
    float4 v = ((const float4*)W)[i];
    unsigned short r0 = f2bf(v.x), r1 = f2bf(v.y), r2 = f2bf(v.z), r3 = f2bf(v.w);
    unsigned long long packed = (unsigned long long)r0 | ((unsigned long long)r1 << 16) |
                                ((unsigned long long)r2 << 32) | ((unsigned long long)r3 << 48);
    ((unsigned long long*)Wb)[i] = packed;
}

__global__ __launch_bounds__(256) void joiner_kernel(
    const float* __restrict__ enc,         // [B,T,D]
    const float* __restrict__ pred,        // [B,U,D]
    const unsigned short* __restrict__ Wb, // [V,D] bf16 bits
    const float* __restrict__ bias,        // [V]
    float* __restrict__ out)               // [B,T,U,V]
{
    // W v-half in LDS: 64 rows x 256 d (bf16) as 16B granules; granule g of
    // row v stored at g ^ (v&7); read pattern (kk*4+lq)^(l16&7) (R4/R5-proven
    // 0-conflict pattern).
    __shared__ unsigned short Wl[64 * 256];   // 32 KB

    const int bid = blockIdx.x;            // ((b*64 + tc)*2 + uh)*2 + vh
    const int vh  = bid & 1;
    const int uh  = (bid >> 1) & 1;
    const int tc  = (bid >> 2) & 63;
    const int b   = bid >> 8;
    const int tid = threadIdx.x;
    const int w   = tid >> 6;              // wave 0..3 -> u rows [w*16, w*16+16)
    const int l16 = tid & 15;
    const int lq  = (tid >> 4) & 3;

    // ---- stage W half (rows vh*64 .. +64) into swizzled LDS ----
    {
        const int vloc = tid >> 2;         // 0..63
        const int part = tid & 3;
        const unsigned short* src = Wb + (size_t)(vh * 64 + vloc) * Dn + part * 64;
#pragma unroll
        for (int i = 0; i < 8; ++i) {
            bf16x8 q = *(const bf16x8*)(src + i * 8);
            const int g = (part * 8 + i) ^ (vloc & 7);
            *(bf16x8*)&Wl[((size_t)vloc * 32 + g) * 8] = q;
        }
    }

    // ---- pred row for this lane, bf16, already in MFMA B-frag layout ----
    const int u = uh * 64 + w * 16 + l16;  // B-operand n-index = l16
    bf16x8 predR[8];                       // [kk]: d = kk*32 + lq*8 .. +7
    {
        const float* pr = pred + ((size_t)(b * Un + u)) * Dn + lq * 8;
#pragma unroll
        for (int kk = 0; kk < 8; ++kk) {
            float4 a0 = *(const float4*)(pr + kk * 32);
            float4 a1 = *(const float4*)(pr + kk * 32 + 4);
            bf16x8 q;
            q[0] = (short)f2bf(a0.x); q[1] = (short)f2bf(a0.y);
            q[2] = (short)f2bf(a0.z); q[3] = (short)f2bf(a0.w);
            q[4] = (short)f2bf(a1.x); q[5] = (short)f2bf(a1.y);
            q[6] = (short)f2bf(a1.z); q[7] = (short)f2bf(a1.w);
            predR[kk] = q;
        }
    }

    __syncthreads();   // the ONLY barrier: W staging visible to the 4 waves

    const float* encRow0 = enc + ((size_t)(b * Tn + tc * TCHUNK)) * Dn + lq * 8;

    for (int ti = 0; ti < TCHUNK; ++ti) {
        const float* er = encRow0 + (size_t)ti * Dn;

        f32x4 acc[4];                      // v-tiles mt=0..3 (64 v total)
#pragma unroll
        for (int mt = 0; mt < 4; ++mt) acc[mt] = (f32x4){0.f, 0.f, 0.f, 0.f};

#pragma unroll
        for (int kk = 0; kk < 8; ++kk) {
            // enc octet (L1-broadcast: 16 lanes share each address)
            float4 e0 = *(const float4*)(er + kk * 32);
            float4 e1 = *(const float4*)(er + kk * 32 + 4);
            const float ev[8] = {e0.x, e0.y, e0.z, e0.w, e1.x, e1.y, e1.z, e1.w};

            // joint B-frag in registers: tanh(enc+pred) for (u=l16 row, d-octet)
            bf16x8 jf;
#pragma unroll
            for (int i = 0; i < 8; ++i)
                jf[i] = (short)f2bf(fast_tanh(ev[i] + bf2f((unsigned short)predR[kk][i])));

            // A = W v-rows from swizzled LDS; 4 MFMAs accumulate 64 v
#pragma unroll
            for (int mt = 0; mt < 4; ++mt) {
                const int row = mt * 16 + l16;
                bf16x8 wf = *(const bf16x8*)&Wl[((size_t)row * 32
                                                 + ((kk * 4 + lq) ^ (l16 & 7))) * 8];
                acc[mt] = __builtin_amdgcn_mfma_f32_16x16x32_bf16(wf, jf, acc[mt], 0, 0, 0);
            }
        }

        // epilogue: D row = v-in-tile = lq*4+r (float4 along v), col = u = l16
        float* ob = out + ((size_t)((b * Tn + tc * TCHUNK + ti) * Un + u)) * Vn
                        + vh * 64 + lq * 4;
#pragma unroll
        for (int mt = 0; mt < 4; ++mt) {
            float4 bv = *(const float4*)(bias + vh * 64 + mt * 16 + lq * 4);
            f32x4 rv;
            rv[0] = acc[mt][0] + bv.x;
            rv[1] = acc[mt][1] + bv.y;
            rv[2] = acc[mt][2] + bv.z;
            rv[3] = acc[mt][3] + bv.w;
            *(f32x4*)(ob + mt * 16) = rv;
        }
    }
}

extern "C" void kernel_launch(void* const* d_in, const int* in_sizes, int n_in,
                              void* d_out, int out_size, void* d_ws, size_t ws_size,
                              hipStream_t stream) {
    const float* enc  = (const float*)d_in[0];
    const float* pred = (const float*)d_in[1];
    const float* W    = (const float*)d_in[2];
    const float* bias = (const float*)d_in[3];
    float* out = (float*)d_out;
    unsigned short* Wb = (unsigned short*)d_ws;   // 32768 bf16 = 64 KB

    cvtW_kernel<<<32, 256, 0, stream>>>(W, Wb);
    // grid = B * (T/TCHUNK) * 2 u-halves * 2 v-halves = 8*64*2*2 = 2048 blocks
    joiner_kernel<<<2048, 256, 0, stream>>>(enc, pred, Wb, bias, out);
}

// Round 12
// 92.383 us; speedup vs baseline: 7.0299x; 1.8601x over previous
//
#include <hip/hip_runtime.h>
#include <hip/hip_bf16.h>

// Joiner: out[b,t,u,v] = tanh(enc[b,t,:] + pred[b,u,:]) . W[v,:] + bias[v]
// B=8 T=512 U=128 D=256 V=128, fp32 in/out.
// R12 = R5 dataflow (tanh once -> XOR-swizzled LDS joint tile; W+pred+bias in
// registers; one lgkmcnt-only s_barrier per t-iter; stores never drained)
// resized for TWO co-resident blocks/CU so the phases of independent blocks
// overlap (R5 had 1 block/CU -> phases summed to 92us):
//  - block = (b, 16-t chunk, u-QUARTER of 32): joint tile 32x256 bf16 = 16 KB,
//    double-buffered = 32 KB LDS (was 64 KB).
//  - 512 thr = 8 waves, wave w -> v-tile [w*16,w*16+16), 32 u rows, acc = 8 VGPR.
//  - per-thread regs ~95 < 128 => 16 waves/CU = 2 blocks co-resident.
//  - NO __launch_bounds__ min-occupancy arg (R7-R9: forces 64-VGPR cap+spill).

constexpr int Bn = 8, Tn = 512, Un = 128, Dn = 256, Vn = 128;
constexpr int TCHUNK = 16;
constexpr int UQ = 32;                     // u rows per block (u-quarter)

typedef __attribute__((ext_vector_type(8))) short bf16x8;   // 8 bf16 = 4 VGPRs
typedef __attribute__((ext_vector_type(4))) float f32x4;

static __device__ __forceinline__ unsigned short f2bf(float f) {
    unsigned int u = __float_as_uint(f);
    return (unsigned short)((u + 0x7fffu + ((u >> 16) & 1u)) >> 16);
}
static __device__ __forceinline__ float bf2f(unsigned short h) {
    return __uint_as_float(((unsigned int)h) << 16);
}
// tanh(x) = 1 - 2/(exp(2x)+1); no clamp: e->inf => 1, e->0 => -1 (exact limits)
static __device__ __forceinline__ float fast_tanh(float x) {
    float e = __expf(2.f * x);
    float r = __builtin_amdgcn_rcpf(e + 1.f);
    return __builtin_fmaf(-2.f, r, 1.f);
}

__global__ __launch_bounds__(256) void cvtW_kernel(const float* __restrict__ W,
                                                   unsigned short* __restrict__ Wb) {
    int i = blockIdx.x * 256 + threadIdx.x;          // 32 blocks * 256 * 4 elems = 32768
    float4 v = ((const float4*)W)[i];
    unsigned short r0 = f2bf(v.x), r1 = f2bf(v.y), r2 = f2bf(v.z), r3 = f2bf(v.w);
    unsigned long long packed = (unsigned long long)r0 | ((unsigned long long)r1 << 16) |
                                ((unsigned long long)r2 << 32) | ((unsigned long long)r3 << 48);
    ((unsigned long long*)Wb)[i] = packed;
}

__global__ __launch_bounds__(512) void joiner_kernel(
    const float* __restrict__ enc,         // [B,T,D]
    const float* __restrict__ pred,        // [B,U,D]
    const unsigned short* __restrict__ Wb, // [V,D] bf16 bits
    const float* __restrict__ bias,        // [V]
    float* __restrict__ out)               // [B,T,U,V]
{
    // joint tile: 32 u-rows x 256 d (bf16) as 16B granules, granule ^= (row&7)
    // swizzle; write pattern (db*2)^sw / read pattern (kk*4+lq)^(l16&7) both
    // measured 0-conflict in R4.
    __shared__ unsigned short jointS[2][UQ * 256];   // 2 x 16 KB

    const int bid = blockIdx.x;            // (b*32 + tc)*4 + q
    const int q   = bid & 3;               // u-quarter
    const int tc  = (bid >> 2) & 31;
    const int b   = bid >> 7;
    const int tid = threadIdx.x;
    const int w   = tid >> 6;              // wave 0..7 -> v-tile [w*16, w*16+16)
    const int l16 = tid & 15;
    const int lq  = (tid >> 4) & 3;

    // phase-1 static mapping: thread owns row ur x 16 d at d0 = db*16
    const int db = tid & 15;
    const int ur = tid >> 4;               // 0..31

    // ---- persistent state (loaded once per block) ----
    bf16x8 predR[2];                       // 1 row x 16 d, bf16 (8 VGPR)
    {
        const float* pr = pred + ((size_t)(b * Un + q * UQ + ur)) * Dn + db * 16;
        float4 a0 = *(const float4*)(pr + 0);
        float4 a1 = *(const float4*)(pr + 4);
        float4 a2 = *(const float4*)(pr + 8);
        float4 a3 = *(const float4*)(pr + 12);
        bf16x8 q0, q1;
        q0[0] = (short)f2bf(a0.x); q0[1] = (short)f2bf(a0.y);
        q0[2] = (short)f2bf(a0.z); q0[3] = (short)f2bf(a0.w);
        q0[4] = (short)f2bf(a1.x); q0[5] = (short)f2bf(a1.y);
        q0[6] = (short)f2bf(a1.z); q0[7] = (short)f2bf(a1.w);
        q1[0] = (short)f2bf(a2.x); q1[1] = (short)f2bf(a2.y);
        q1[2] = (short)f2bf(a2.z); q1[3] = (short)f2bf(a2.w);
        q1[4] = (short)f2bf(a3.x); q1[5] = (short)f2bf(a3.y);
        q1[6] = (short)f2bf(a3.z); q1[7] = (short)f2bf(a3.w);
        predR[0] = q0; predR[1] = q1;
    }

    bf16x8 wfr[8];                         // W A-frags: wave's 16 v rows x K=256 (32 VGPR)
#pragma unroll
    for (int kk = 0; kk < 8; ++kk)
        wfr[kk] = *(const bf16x8*)(Wb + (size_t)(w * 16 + l16) * Dn + kk * 32 + lq * 8);

    const float4 bv = *(const float4*)(bias + w * 16 + lq * 4);

    const size_t encBase = (size_t)(b * Tn + tc * TCHUNK) * Dn;

    // tanh(enc + pred) -> swizzled LDS tile (each value computed exactly once)
    auto write_tile = [&](unsigned short* buf, const float ev[16]) {
        const int sw = ur & 7;
        bf16x8 o0, o1;
#pragma unroll
        for (int i = 0; i < 8; ++i)
            o0[i] = (short)f2bf(fast_tanh(ev[i] + bf2f((unsigned short)predR[0][i])));
#pragma unroll
        for (int i = 0; i < 8; ++i)
            o1[i] = (short)f2bf(fast_tanh(ev[8 + i] + bf2f((unsigned short)predR[1][i])));
        *(bf16x8*)&buf[((ur * 32) + ((db * 2) ^ sw)) * 8]     = o0;
        *(bf16x8*)&buf[((ur * 32) + ((db * 2 + 1) ^ sw)) * 8] = o1;
    };
    auto load_enc = [&](int t_idx, float ev[16]) {
        const float* er = enc + encBase + (size_t)t_idx * Dn + db * 16;
        float4 a0 = *(const float4*)(er + 0);
        float4 a1 = *(const float4*)(er + 4);
        float4 a2 = *(const float4*)(er + 8);
        float4 a3 = *(const float4*)(er + 12);
        ev[0] = a0.x;  ev[1] = a0.y;  ev[2]  = a0.z;  ev[3]  = a0.w;
        ev[4] = a1.x;  ev[5] = a1.y;  ev[6]  = a1.z;  ev[7]  = a1.w;
        ev[8] = a2.x;  ev[9] = a2.y;  ev[10] = a2.z;  ev[11] = a2.w;
        ev[12] = a3.x; ev[13] = a3.y; ev[14] = a3.z;  ev[15] = a3.w;
    };

    // ---- prologue: tile 0 into buf 0 ----
    {
        float ev[16];
        load_enc(0, ev);
        write_tile(jointS[0], ev);
    }
    asm volatile("s_waitcnt lgkmcnt(0)" ::: "memory");
    __builtin_amdgcn_s_barrier();
    __builtin_amdgcn_sched_barrier(0);

    for (int ti = 0; ti < TCHUNK; ++ti) {
        const unsigned short* cur = jointS[ti & 1];

        // prefetch enc[ti+1] (latency hides under the MFMA phase)
        float ev[16];
        if (ti + 1 < TCHUNK) load_enc(ti + 1, ev);

        // ---------- MFMA: A = W regs (16 v), B = joint tile (32 u) ----------
        f32x4 acc[2];
#pragma unroll
        for (int ut = 0; ut < 2; ++ut) acc[ut] = (f32x4){0.f, 0.f, 0.f, 0.f};

#pragma unroll
        for (int kk = 0; kk < 8; ++kk) {
            bf16x8 bfr[2];
#pragma unroll
            for (int ut = 0; ut < 2; ++ut) {
                const int row = ut * 16 + l16;
                bfr[ut] = *(const bf16x8*)&cur[((row * 32) + ((kk * 4 + lq) ^ (l16 & 7))) * 8];
            }
#pragma unroll
            for (int ut = 0; ut < 2; ++ut)
                acc[ut] = __builtin_amdgcn_mfma_f32_16x16x32_bf16(wfr[kk], bfr[ut], acc[ut], 0, 0, 0);
        }

        // ---------- epilogue: bias + float4 stores (never drained in-loop) ----------
        // D row = v = w*16 + lq*4 + r, col = u-in-tile = ut*16 + l16
        const size_t rowBase = (size_t)((b * Tn + tc * TCHUNK + ti) * Un + q * UQ);
#pragma unroll
        for (int ut = 0; ut < 2; ++ut) {
            float* ob = out + (rowBase + ut * 16 + l16) * Vn + w * 16 + lq * 4;
            f32x4 rv;
            rv[0] = acc[ut][0] + bv.x;
            rv[1] = acc[ut][1] + bv.y;
            rv[2] = acc[ut][2] + bv.z;
            rv[3] = acc[ut][3] + bv.w;
            *(f32x4*)ob = rv;
        }

        // ---------- next tanh tile into the other buffer ----------
        if (ti + 1 < TCHUNK) {
            write_tile(jointS[(ti + 1) & 1], ev);
            // barrier protects LDS only: wait ds ops, NOT the global stores
            asm volatile("s_waitcnt lgkmcnt(0)" ::: "memory");
            __builtin_amdgcn_s_barrier();
            __builtin_amdgcn_sched_barrier(0);
        }
    }
}

extern "C" void kernel_launch(void* const* d_in, const int* in_sizes, int n_in,
                              void* d_out, int out_size, void* d_ws, size_t ws_size,
                              hipStream_t stream) {
    const float* enc  = (const float*)d_in[0];
    const float* pred = (const float*)d_in[1];
    const float* W    = (const float*)d_in[2];
    const float* bias = (const float*)d_in[3];
    float* out = (float*)d_out;
    unsigned short* Wb = (unsigned short*)d_ws;   // 32768 bf16 = 64 KB

    cvtW_kernel<<<32, 256, 0, stream>>>(W, Wb);
    // grid = B * (T/TCHUNK) * 4 u-quarters = 8 * 32 * 4 = 1024 blocks
    joiner_kernel<<<1024, 512, 0, stream>>>(enc, pred, Wb, bias, out);
}